// Round 2
// baseline (759.236 us; speedup 1.0000x reference)
//
#include <hip/hip_runtime.h>
#include <hip/hip_bf16.h>

#define ND 2048

using bf16 = __hip_bfloat16;
using short8 = __attribute__((ext_vector_type(8))) short;   // 8 bf16 = 4 VGPRs
using floatx4 = __attribute__((ext_vector_type(4))) float;

// ---------------- elementwise kernels ----------------

// M = 0.5*(u^T - u) (this is A.T of the reference), fp32 in -> bf16 out.
__global__ void build_skew(const float* __restrict__ u, bf16* __restrict__ M) {
    __shared__ float t[32][33];
    const int bx = blockIdx.x & (ND / 32 - 1);
    const int by = blockIdx.x / (ND / 32);
    const int tx = threadIdx.x & 31;
    const int ty = threadIdx.x >> 5;   // 0..7
#pragma unroll
    for (int rr = 0; rr < 4; ++rr) {
        const int r = ty * 4 + rr;
        t[tx][r] = u[(size_t)(bx * 32 + r) * ND + by * 32 + tx];
    }
    __syncthreads();
#pragma unroll
    for (int rr = 0; rr < 4; ++rr) {
        const int r = ty * 4 + rr;
        const size_t idx = (size_t)(by * 32 + r) * ND + bx * 32 + tx;
        const float v = 0.5f * (t[r][tx] - u[idx]);
        M[idx] = __float2bfloat16(v);
    }
}

// Hoff = 2M + Msq ; HoffT = -2M + Msq  (= Hoff^T since M skew, Msq symmetric).
// HoffT may alias M (same-index read-before-write) -> no __restrict__.
__global__ void build_hoff(const bf16* M, const bf16* Msq, bf16* Hoff, bf16* HoffT) {
    const size_t idx = (size_t)blockIdx.x * 256 + threadIdx.x;
    const float m = __bfloat162float(M[idx]);
    const float q = __bfloat162float(Msq[idx]);
    Hoff[idx] = __float2bfloat16(2.f * m + q);
    HoffT[idx] = __float2bfloat16(q - 2.f * m);
}

// ---------------- GEMM: C = A @ Bt^T, bf16 MFMA, fp32 accumulate ----------------
// 128x128 tile, BK=32, 256 threads (4 waves, 2x2 of 64x64), 16x16x32 bf16 MFMA.
// AF32: A operand is fp32 in global, converted to bf16 during LDS staging.
// OF32: C stored as fp32 (final output), else bf16 (internal buffers).

enum { EPI_PLAIN = 0, EPI_NEG = 1, EPI_ADD1 = 2, EPI_P = 3, EPI_P_ROT = 4 };

template <int EPI, bool AF32, bool OF32>
__launch_bounds__(256, 2) __global__
void gemm_bt(const void* __restrict__ Ap, const bf16* __restrict__ Bt,
             void* __restrict__ Cp, const int Nc, const int K,
             const bf16* __restrict__ add1, const bf16* __restrict__ add2,
             const float* __restrict__ thetaP)
{
    __shared__ __attribute__((aligned(16))) short aT[128 * 32];
    __shared__ __attribute__((aligned(16))) short bT[128 * 32];

    const int nblk = Nc >> 7;
    const int bx = blockIdx.x % nblk;
    const int by = blockIdx.x / nblk;
    const int tid = threadIdx.x;
    const int lane = tid & 63;
    const int quad = lane >> 4;
    const int l15 = lane & 15;
    const int wv = tid >> 6;
    const int wr = (wv >> 1) << 6;   // wave row offset: 0 or 64
    const int wc = (wv & 1) << 6;    // wave col offset: 0 or 64

    const short* Ag = (const short*)Ap + (size_t)(by << 7) * K;   // bf16 path
    const float* Agf = (const float*)Ap + (size_t)(by << 7) * K;  // fp32 path
    const short* Bg = (const short*)Bt + (size_t)(bx << 7) * K;

    floatx4 acc[4][4];
#pragma unroll
    for (int i = 0; i < 4; ++i)
#pragma unroll
        for (int j = 0; j < 4; ++j)
            acc[i][j] = (floatx4){0.f, 0.f, 0.f, 0.f};

    for (int k0 = 0; k0 < K; k0 += 32) {
        // stage 128x32 A-tile and Bt-tile: 512 chunks of 8 bf16 each, 2 per thread
#pragma unroll
        for (int c = 0; c < 2; ++c) {
            const int ch = tid + (c << 8);
            const int row = ch >> 2;
            const int kp = (ch & 3) << 3;
            if (AF32) {
                const float4 f0 = *(const float4*)(Agf + (size_t)row * K + k0 + kp);
                const float4 f1 = *(const float4*)(Agf + (size_t)row * K + k0 + kp + 4);
                short8 pk;
                pk[0] = __builtin_bit_cast(short, __float2bfloat16(f0.x));
                pk[1] = __builtin_bit_cast(short, __float2bfloat16(f0.y));
                pk[2] = __builtin_bit_cast(short, __float2bfloat16(f0.z));
                pk[3] = __builtin_bit_cast(short, __float2bfloat16(f0.w));
                pk[4] = __builtin_bit_cast(short, __float2bfloat16(f1.x));
                pk[5] = __builtin_bit_cast(short, __float2bfloat16(f1.y));
                pk[6] = __builtin_bit_cast(short, __float2bfloat16(f1.z));
                pk[7] = __builtin_bit_cast(short, __float2bfloat16(f1.w));
                *(short8*)(aT + (row << 5) + kp) = pk;
            } else {
                const int4 av = *(const int4*)(Ag + (size_t)row * K + k0 + kp);
                *(int4*)(aT + (row << 5) + kp) = av;
            }
            const int4 bv = *(const int4*)(Bg + (size_t)row * K + k0 + kp);
            *(int4*)(bT + (row << 5) + kp) = bv;
        }
        __syncthreads();
        short8 af[4], bfr[4];
#pragma unroll
        for (int mi = 0; mi < 4; ++mi)
            af[mi] = *(const short8*)(aT + ((wr + (mi << 4) + l15) << 5) + (quad << 3));
#pragma unroll
        for (int ni = 0; ni < 4; ++ni)
            bfr[ni] = *(const short8*)(bT + ((wc + (ni << 4) + l15) << 5) + (quad << 3));
#pragma unroll
        for (int mi = 0; mi < 4; ++mi)
#pragma unroll
            for (int ni = 0; ni < 4; ++ni)
                acc[mi][ni] = __builtin_amdgcn_mfma_f32_16x16x32_bf16(af[mi], bfr[ni], acc[mi][ni], 0, 0, 0);
        __syncthreads();
    }

    float ct = 0.f, st = 0.f;
    if (EPI == EPI_P_ROT) {
        const float th = *thetaP;
        ct = cosf(th);
        st = sinf(th);
    }

    // C/D layout (m89-verified): col = lane&15, row = quad*4 + reg
#pragma unroll
    for (int mi = 0; mi < 4; ++mi) {
#pragma unroll
        for (int ni = 0; ni < 4; ++ni) {
#pragma unroll
            for (int r = 0; r < 4; ++r) {
                const int row = (by << 7) + wr + (mi << 4) + (quad << 2) + r;
                const int col = (bx << 7) + wc + (ni << 4) + l15;
                const size_t idx = (size_t)row * Nc + col;
                float v = acc[mi][ni][r];
                if (EPI == EPI_NEG) v = -v;
                if (EPI == EPI_ADD1) v += __bfloat162float(add1[idx]);
                if (EPI == EPI_P || EPI == EPI_P_ROT)
                    v += (row == col ? 1.f : 0.f)
                       + __bfloat162float(add1[idx]) + __bfloat162float(add2[idx]);
                if (EPI == EPI_P_ROT) {
                    // adjacent columns live in adjacent lanes; pairwise rotate
                    const float w = __shfl_xor(v, 1, 64);
                    v = (l15 & 1) ? (st * w + ct * v) : (ct * v - st * w);
                }
                if (OF32) ((float*)Cp)[idx] = v;
                else      ((bf16*)Cp)[idx] = __float2bfloat16(v);
            }
        }
    }
}

// ---------------- launch ----------------
// out = x @ P1 @ R @ P2, P = (I+M)^2 (I+M^2+M^4), M = 0.5(W^T - W)
// Workspace: 5 bf16 buffers of ND*ND (= 41.9 MB total).

extern "C" void kernel_launch(void* const* d_in, const int* in_sizes, int n_in,
                              void* d_out, int out_size, void* d_ws, size_t ws_size,
                              hipStream_t stream)
{
    const float* x = (const float*)d_in[0];
    const float* u1 = (const float*)d_in[1];
    const float* u2 = (const float*)d_in[2];
    const float* th = (const float*)d_in[3];
    float* out = (float*)d_out;
    const int tokens = in_sizes[0] / ND;

    const size_t MAT = (size_t)ND * ND;
    bf16* A = (bf16*)d_ws;
    bf16* B = A + MAT;
    bf16* Cb = B + MAT;
    bf16* D = Cb + MAT;
    bf16* E = D + MAT;

    const dim3 blk(256);
    const int gSkew = (ND / 32) * (ND / 32);
    const int gElem = (int)(MAT / 256);
    const int gSm = (ND / 128) * (ND / 128);
    const int gBig = (tokens / 128) * (ND / 128);

    // ---- matrix 2 first (so P2T lands in a buffer freed for matrix 1) ----
    build_skew<<<gSkew, blk, 0, stream>>>(u2, A);                                   // A = M2
    gemm_bt<EPI_NEG, false, false><<<gSm, blk, 0, stream>>>(A, A, B, ND, ND, nullptr, nullptr, nullptr);   // B = Msq2
    gemm_bt<EPI_ADD1, false, false><<<gSm, blk, 0, stream>>>(B, B, Cb, ND, ND, B, nullptr, nullptr);       // Cb = Goff2
    build_hoff<<<gElem, blk, 0, stream>>>(A, B, D, E);                              // D = Hoff2, E = HoffT2
    // P2T = G2 @ H2^T = I + Goff2 + HoffT2 + Goff2@Hoff2^T   -> A (M2 dead)
    gemm_bt<EPI_P, false, false><<<gSm, blk, 0, stream>>>(Cb, D, A, ND, ND, Cb, E, nullptr);   // A = P2T

    // ---- matrix 1 ----
    build_skew<<<gSkew, blk, 0, stream>>>(u1, B);                                   // B = M1
    gemm_bt<EPI_NEG, false, false><<<gSm, blk, 0, stream>>>(B, B, Cb, ND, ND, nullptr, nullptr, nullptr);  // Cb = Msq1
    gemm_bt<EPI_ADD1, false, false><<<gSm, blk, 0, stream>>>(Cb, Cb, D, ND, ND, Cb, nullptr, nullptr);     // D = Goff1
    build_hoff<<<gElem, blk, 0, stream>>>(B, Cb, E, B);                             // E = Hoff1 (HoffT1->B, dead)
    // P1R = (I + Goff1 + Hoff1 + Hoff1@Goff1) @ R   -> Cb (Msq1 dead)
    gemm_bt<EPI_P_ROT, false, false><<<gSm, blk, 0, stream>>>(E, D, Cb, ND, ND, D, E, th);     // Cb = P1R

    // QT = P2T @ (P1R)^T   -> D (Goff1 dead)
    gemm_bt<EPI_PLAIN, false, false><<<gSm, blk, 0, stream>>>(A, Cb, D, ND, ND, nullptr, nullptr, nullptr);

    // out = x @ QT^T = x @ Q   (A operand fp32 -> bf16 staging; fp32 store)
    gemm_bt<EPI_PLAIN, true, true><<<gBig, blk, 0, stream>>>(x, D, out, ND, ND, nullptr, nullptr, nullptr);
}

// Round 3
// 616.651 us; speedup vs baseline: 1.2312x; 1.2312x over previous
//
#include <hip/hip_runtime.h>
#include <hip/hip_bf16.h>

#define ND 2048

using bf16 = __hip_bfloat16;
using short8 = __attribute__((ext_vector_type(8))) short;   // 8 bf16 = 4 VGPRs
using floatx4 = __attribute__((ext_vector_type(4))) float;

// ---------------- async global->LDS (16B per lane, wave-uniform LDS base) ----
__device__ __forceinline__ void gl2lds16(const short* g, short* l) {
    __builtin_amdgcn_global_load_lds(
        (const __attribute__((address_space(1))) unsigned int*)g,
        (__attribute__((address_space(3))) unsigned int*)l,
        16, 0, 0);
}

// ---------------- elementwise kernels ----------------

// M = 0.5*(u^T - u) (this is A.T of the reference), fp32 in -> bf16 out.
__global__ void build_skew(const float* __restrict__ u, bf16* __restrict__ M) {
    __shared__ float t[32][33];
    const int bx = blockIdx.x & (ND / 32 - 1);
    const int by = blockIdx.x / (ND / 32);
    const int tx = threadIdx.x & 31;
    const int ty = threadIdx.x >> 5;   // 0..7
#pragma unroll
    for (int rr = 0; rr < 4; ++rr) {
        const int r = ty * 4 + rr;
        t[tx][r] = u[(size_t)(bx * 32 + r) * ND + by * 32 + tx];
    }
    __syncthreads();
#pragma unroll
    for (int rr = 0; rr < 4; ++rr) {
        const int r = ty * 4 + rr;
        const size_t idx = (size_t)(by * 32 + r) * ND + bx * 32 + tx;
        M[idx] = __float2bfloat16(0.5f * (t[r][tx] - u[idx]));
    }
}

// Hoff = 2M + Msq (may alias Msq same-index -> no __restrict__ on those)
__global__ void build_hoff1(const bf16* __restrict__ M, const bf16* Msq, bf16* Hoff) {
    const size_t idx = (size_t)blockIdx.x * 256 + threadIdx.x;
    const float m = __bfloat162float(M[idx]);
    const float q = __bfloat162float(Msq[idx]);
    Hoff[idx] = __float2bfloat16(2.f * m + q);
}

// Tier-B variant: also emits HoffT = -2M + Msq (HoffT may alias M)
__global__ void build_hoff(const bf16* M, const bf16* Msq, bf16* Hoff, bf16* HoffT) {
    const size_t idx = (size_t)blockIdx.x * 256 + threadIdx.x;
    const float m = __bfloat162float(M[idx]);
    const float q = __bfloat162float(Msq[idx]);
    Hoff[idx] = __float2bfloat16(2.f * m + q);
    HoffT[idx] = __float2bfloat16(q - 2.f * m);
}

// x fp32 -> bf16, 8 elems/thread
__global__ void convert_f32_bf16(const float* __restrict__ x, bf16* __restrict__ y) {
    const size_t base = ((size_t)blockIdx.x * 256 + threadIdx.x) * 8;
    const float4 f0 = *(const float4*)(x + base);
    const float4 f1 = *(const float4*)(x + base + 4);
    short8 pk;
    pk[0] = __builtin_bit_cast(short, __float2bfloat16(f0.x));
    pk[1] = __builtin_bit_cast(short, __float2bfloat16(f0.y));
    pk[2] = __builtin_bit_cast(short, __float2bfloat16(f0.z));
    pk[3] = __builtin_bit_cast(short, __float2bfloat16(f0.w));
    pk[4] = __builtin_bit_cast(short, __float2bfloat16(f1.x));
    pk[5] = __builtin_bit_cast(short, __float2bfloat16(f1.y));
    pk[6] = __builtin_bit_cast(short, __float2bfloat16(f1.z));
    pk[7] = __builtin_bit_cast(short, __float2bfloat16(f1.w));
    *(short8*)((short*)y + base) = pk;
}

// ---------------- epilogue modes ----------------
enum { EPI_PLAIN = 0, EPI_NEG = 1, EPI_ADD1 = 2, EPI_P = 3, EPI_P_ROT = 4, EPI_PT = 5 };
// EPI_PT: C = acc + I + add1 + add2^T   (transposed add2 read, kills HoffT buffer)

// ---------------- async-staged GEMM core: C = A @ Bt^T ----------------
// 128x128 tile, BK=32, 256 threads, global_load_lds dwordx4 staging (m97 structure).
template <int EPI, bool OF32>
__device__ __forceinline__ void gemm_core(
    short* aT, short* bT,
    const bf16* __restrict__ A, const bf16* __restrict__ Bt, void* __restrict__ Cp,
    const int Nc, const int K, const int bx, const int by,
    const bf16* __restrict__ add1, const bf16* __restrict__ add2,
    const float* __restrict__ thetaP)
{
    const int tid = threadIdx.x;
    const int lane = tid & 63;
    const int quad = lane >> 4;
    const int l15 = lane & 15;
    const int wv = tid >> 6;
    const int wr = (wv >> 1) << 6;   // wave row offset: 0 or 64
    const int wc = (wv & 1) << 6;    // wave col offset: 0 or 64

    const short* Ag = (const short*)A + (size_t)(by << 7) * K;
    const short* Bg = (const short*)Bt + (size_t)(bx << 7) * K;

    floatx4 acc[4][4];
#pragma unroll
    for (int i = 0; i < 4; ++i)
#pragma unroll
        for (int j = 0; j < 4; ++j)
            acc[i][j] = (floatx4){0.f, 0.f, 0.f, 0.f};

    for (int k0 = 0; k0 < K; k0 += 32) {
        // 128x32 tiles = 512 x 16B chunks each; 2 chunks/thread, async DMA.
        // chunk ch -> LDS shorts [ch*8, ch*8+8) ; wave-uniform base + lane*16B.
#pragma unroll
        for (int c = 0; c < 2; ++c) {
            const int ch = (c << 8) + (wv << 6) + lane;
            const int row = ch >> 2;
            const int kp = (ch & 3) << 3;                 // short offset in row
            const int ldsBase = ((c << 8) + (wv << 6)) << 3;  // shorts, wave-uniform
            gl2lds16(Ag + (size_t)row * K + k0 + kp, aT + ldsBase);
            gl2lds16(Bg + (size_t)row * K + k0 + kp, bT + ldsBase);
        }
        __syncthreads();
        short8 af[4], bfr[4];
#pragma unroll
        for (int mi = 0; mi < 4; ++mi)
            af[mi] = *(const short8*)(aT + ((wr + (mi << 4) + l15) << 5) + (quad << 3));
#pragma unroll
        for (int ni = 0; ni < 4; ++ni)
            bfr[ni] = *(const short8*)(bT + ((wc + (ni << 4) + l15) << 5) + (quad << 3));
#pragma unroll
        for (int mi = 0; mi < 4; ++mi)
#pragma unroll
            for (int ni = 0; ni < 4; ++ni)
                acc[mi][ni] = __builtin_amdgcn_mfma_f32_16x16x32_bf16(af[mi], bfr[ni], acc[mi][ni], 0, 0, 0);
        __syncthreads();
    }

    float ct = 0.f, st = 0.f;
    if (EPI == EPI_P_ROT) {
        const float th = *thetaP;
        ct = cosf(th);
        st = sinf(th);
    }

    // C/D layout (m89-verified): col = lane&15, row = quad*4 + reg
#pragma unroll
    for (int mi = 0; mi < 4; ++mi) {
#pragma unroll
        for (int ni = 0; ni < 4; ++ni) {
#pragma unroll
            for (int r = 0; r < 4; ++r) {
                const int row = (by << 7) + wr + (mi << 4) + (quad << 2) + r;
                const int col = (bx << 7) + wc + (ni << 4) + l15;
                const size_t idx = (size_t)row * Nc + col;
                float v = acc[mi][ni][r];
                if (EPI == EPI_NEG) v = -v;
                if (EPI == EPI_ADD1) v += __bfloat162float(add1[idx]);
                if (EPI == EPI_P)
                    v += (row == col ? 1.f : 0.f)
                       + __bfloat162float(add1[idx]) + __bfloat162float(add2[idx]);
                if (EPI == EPI_PT)
                    v += (row == col ? 1.f : 0.f)
                       + __bfloat162float(add1[idx])
                       + __bfloat162float(add2[(size_t)col * Nc + row]);
                if (EPI == EPI_P_ROT) {
                    v += (row == col ? 1.f : 0.f)
                       + __bfloat162float(add1[idx]) + __bfloat162float(add2[idx]);
                    const float w = __shfl_xor(v, 1, 64);
                    v = (l15 & 1) ? (st * w + ct * v) : (ct * v - st * w);
                }
                if (OF32) ((float*)Cp)[idx] = v;
                else      ((bf16*)Cp)[idx] = __float2bfloat16(v);
            }
        }
    }
}

template <int EPI, bool OF32>
__launch_bounds__(256, 2) __global__
void gemm_one(const bf16* __restrict__ A, const bf16* __restrict__ Bt,
              void* __restrict__ Cp, const int Nc, const int K,
              const bf16* __restrict__ add1, const bf16* __restrict__ add2,
              const float* __restrict__ thetaP)
{
    __shared__ __attribute__((aligned(16))) short aT[128 * 32];
    __shared__ __attribute__((aligned(16))) short bT[128 * 32];
    const int nblk = Nc >> 7;
    gemm_core<EPI, OF32>(aT, bT, A, Bt, Cp, Nc, K, blockIdx.x % nblk, blockIdx.x / nblk,
                         add1, add2, thetaP);
}

// Two independent 2048^2 GEMMs in one dispatch (grid = 512 -> 2 blocks/CU).
template <int EPI0, int EPI1>
__launch_bounds__(256, 2) __global__
void gemm_dual(const bf16* A0, const bf16* B0, bf16* C0, const bf16* a10, const bf16* a20,
               const bf16* A1, const bf16* B1, bf16* C1, const bf16* a11, const bf16* a21,
               const float* thetaP)
{
    __shared__ __attribute__((aligned(16))) short aT[128 * 32];
    __shared__ __attribute__((aligned(16))) short bT[128 * 32];
    const int nblk = ND >> 7;          // 16
    const int nsub = nblk * nblk;      // 256
    int b = blockIdx.x;
    if (b < nsub) {
        gemm_core<EPI0, false>(aT, bT, A0, B0, (void*)C0, ND, ND, b % nblk, b / nblk, a10, a20, thetaP);
    } else {
        b -= nsub;
        gemm_core<EPI1, false>(aT, bT, A1, B1, (void*)C1, ND, ND, b % nblk, b / nblk, a11, a21, thetaP);
    }
}

// ---------------- Tier-B (round-2 proven) manual-staging GEMM ----------------
template <int EPI, bool AF32, bool OF32>
__launch_bounds__(256, 2) __global__
void gemm_bt(const void* __restrict__ Ap, const bf16* __restrict__ Bt,
             void* __restrict__ Cp, const int Nc, const int K,
             const bf16* __restrict__ add1, const bf16* __restrict__ add2,
             const float* __restrict__ thetaP)
{
    __shared__ __attribute__((aligned(16))) short aT[128 * 32];
    __shared__ __attribute__((aligned(16))) short bT[128 * 32];

    const int nblk = Nc >> 7;
    const int bx = blockIdx.x % nblk;
    const int by = blockIdx.x / nblk;
    const int tid = threadIdx.x;
    const int lane = tid & 63;
    const int quad = lane >> 4;
    const int l15 = lane & 15;
    const int wv = tid >> 6;
    const int wr = (wv >> 1) << 6;
    const int wc = (wv & 1) << 6;

    const short* Ag = (const short*)Ap + (size_t)(by << 7) * K;
    const float* Agf = (const float*)Ap + (size_t)(by << 7) * K;
    const short* Bg = (const short*)Bt + (size_t)(bx << 7) * K;

    floatx4 acc[4][4];
#pragma unroll
    for (int i = 0; i < 4; ++i)
#pragma unroll
        for (int j = 0; j < 4; ++j)
            acc[i][j] = (floatx4){0.f, 0.f, 0.f, 0.f};

    for (int k0 = 0; k0 < K; k0 += 32) {
#pragma unroll
        for (int c = 0; c < 2; ++c) {
            const int ch = tid + (c << 8);
            const int row = ch >> 2;
            const int kp = (ch & 3) << 3;
            if (AF32) {
                const float4 f0 = *(const float4*)(Agf + (size_t)row * K + k0 + kp);
                const float4 f1 = *(const float4*)(Agf + (size_t)row * K + k0 + kp + 4);
                short8 pk;
                pk[0] = __builtin_bit_cast(short, __float2bfloat16(f0.x));
                pk[1] = __builtin_bit_cast(short, __float2bfloat16(f0.y));
                pk[2] = __builtin_bit_cast(short, __float2bfloat16(f0.z));
                pk[3] = __builtin_bit_cast(short, __float2bfloat16(f0.w));
                pk[4] = __builtin_bit_cast(short, __float2bfloat16(f1.x));
                pk[5] = __builtin_bit_cast(short, __float2bfloat16(f1.y));
                pk[6] = __builtin_bit_cast(short, __float2bfloat16(f1.z));
                pk[7] = __builtin_bit_cast(short, __float2bfloat16(f1.w));
                *(short8*)(aT + (row << 5) + kp) = pk;
            } else {
                *(int4*)(aT + (row << 5) + kp) = *(const int4*)(Ag + (size_t)row * K + k0 + kp);
            }
            *(int4*)(bT + (row << 5) + kp) = *(const int4*)(Bg + (size_t)row * K + k0 + kp);
        }
        __syncthreads();
        short8 af[4], bfr[4];
#pragma unroll
        for (int mi = 0; mi < 4; ++mi)
            af[mi] = *(const short8*)(aT + ((wr + (mi << 4) + l15) << 5) + (quad << 3));
#pragma unroll
        for (int ni = 0; ni < 4; ++ni)
            bfr[ni] = *(const short8*)(bT + ((wc + (ni << 4) + l15) << 5) + (quad << 3));
#pragma unroll
        for (int mi = 0; mi < 4; ++mi)
#pragma unroll
            for (int ni = 0; ni < 4; ++ni)
                acc[mi][ni] = __builtin_amdgcn_mfma_f32_16x16x32_bf16(af[mi], bfr[ni], acc[mi][ni], 0, 0, 0);
        __syncthreads();
    }

    float ct = 0.f, st = 0.f;
    if (EPI == EPI_P_ROT) {
        const float th = *thetaP;
        ct = cosf(th);
        st = sinf(th);
    }

#pragma unroll
    for (int mi = 0; mi < 4; ++mi) {
#pragma unroll
        for (int ni = 0; ni < 4; ++ni) {
#pragma unroll
            for (int r = 0; r < 4; ++r) {
                const int row = (by << 7) + wr + (mi << 4) + (quad << 2) + r;
                const int col = (bx << 7) + wc + (ni << 4) + l15;
                const size_t idx = (size_t)row * Nc + col;
                float v = acc[mi][ni][r];
                if (EPI == EPI_NEG) v = -v;
                if (EPI == EPI_ADD1) v += __bfloat162float(add1[idx]);
                if (EPI == EPI_P || EPI == EPI_P_ROT)
                    v += (row == col ? 1.f : 0.f)
                       + __bfloat162float(add1[idx]) + __bfloat162float(add2[idx]);
                if (EPI == EPI_P_ROT) {
                    const float w = __shfl_xor(v, 1, 64);
                    v = (l15 & 1) ? (st * w + ct * v) : (ct * v - st * w);
                }
                if (OF32) ((float*)Cp)[idx] = v;
                else      ((bf16*)Cp)[idx] = __float2bfloat16(v);
            }
        }
    }
}

// ---------------- launch ----------------
// out = x @ P1 @ R @ P2,  P = (I+M)^2 (I+M^2+M^4),  M = 0.5(W^T - W)
// Tier A (ws >= 6*ND^2*2 + tokens*ND*2 bytes): dual-batched chains + async GEMM + bf16 x.
// Tier B: round-2 proven sequence (5 buffers, fp32 A staging on the big GEMM).

extern "C" void kernel_launch(void* const* d_in, const int* in_sizes, int n_in,
                              void* d_out, int out_size, void* d_ws, size_t ws_size,
                              hipStream_t stream)
{
    const float* x = (const float*)d_in[0];
    const float* u1 = (const float*)d_in[1];
    const float* u2 = (const float*)d_in[2];
    const float* th = (const float*)d_in[3];
    float* out = (float*)d_out;
    const int tokens = in_sizes[0] / ND;

    const size_t MAT = (size_t)ND * ND;
    const size_t XBE = (size_t)tokens * ND;

    const dim3 blk(256);
    const int gSkew = (ND / 32) * (ND / 32);
    const int gElem = (int)(MAT / 256);
    const int gSm = (ND / 128) * (ND / 128);        // 256
    const int gBig = (tokens / 128) * (ND / 128);   // 2048

    if (ws_size >= (6 * MAT + XBE) * sizeof(bf16)) {
        // ---------------- Tier A ----------------
        bf16* base = (bf16*)d_ws;
        bf16* b0 = base;            // M2 -> P2T
        bf16* b1 = base + MAT;      // M1 -> P1R
        bf16* b2 = base + 2 * MAT;  // Msq2 -> Hoff2 -> QT
        bf16* b3 = base + 3 * MAT;  // Msq1 -> Hoff1
        bf16* b4 = base + 4 * MAT;  // Goff2
        bf16* b5 = base + 5 * MAT;  // Goff1
        bf16* xb = base + 6 * MAT;  // x as bf16

        convert_f32_bf16<<<(int)(XBE / 2048), blk, 0, stream>>>(x, xb);
        build_skew<<<gSkew, blk, 0, stream>>>(u2, b0);   // M2
        build_skew<<<gSkew, blk, 0, stream>>>(u1, b1);   // M1
        // Msq = -(M @ M^T)  (M skew)
        gemm_dual<EPI_NEG, EPI_NEG><<<2 * gSm, blk, 0, stream>>>(
            b0, b0, b2, nullptr, nullptr,  b1, b1, b3, nullptr, nullptr, nullptr);
        // Goff = Msq@Msq + Msq   (Msq symmetric)
        gemm_dual<EPI_ADD1, EPI_ADD1><<<2 * gSm, blk, 0, stream>>>(
            b2, b2, b4, b2, nullptr,  b3, b3, b5, b3, nullptr, nullptr);
        // Hoff = 2M + Msq (in place over Msq)
        build_hoff1<<<gElem, blk, 0, stream>>>(b0, b2, b2);   // Hoff2
        build_hoff1<<<gElem, blk, 0, stream>>>(b1, b3, b3);   // Hoff1
        // P2T = I + Goff2 + Hoff2^T + Goff2@Hoff2^T  (PT: transposed add2)
        // P1R = (I + Goff1 + Hoff1 + Hoff1@Goff1) @ R
        gemm_dual<EPI_PT, EPI_P_ROT><<<2 * gSm, blk, 0, stream>>>(
            b4, b2, b0, b4, b2,  b3, b5, b1, b5, b3, th);
        // QT = P2T @ (P1R)^T
        gemm_one<EPI_PLAIN, false><<<gSm, blk, 0, stream>>>(b0, b1, b2, ND, ND, nullptr, nullptr, nullptr);
        // out = x @ QT^T
        gemm_one<EPI_PLAIN, true><<<gBig, blk, 0, stream>>>(xb, b2, out, ND, ND, nullptr, nullptr, nullptr);
    } else {
        // ---------------- Tier B (round-2 proven) ----------------
        bf16* A = (bf16*)d_ws;
        bf16* B = A + MAT;
        bf16* Cb = B + MAT;
        bf16* D = Cb + MAT;
        bf16* E = D + MAT;

        build_skew<<<gSkew, blk, 0, stream>>>(u2, A);
        gemm_bt<EPI_NEG, false, false><<<gSm, blk, 0, stream>>>(A, A, B, ND, ND, nullptr, nullptr, nullptr);
        gemm_bt<EPI_ADD1, false, false><<<gSm, blk, 0, stream>>>(B, B, Cb, ND, ND, B, nullptr, nullptr);
        build_hoff<<<gElem, blk, 0, stream>>>(A, B, D, E);
        gemm_bt<EPI_P, false, false><<<gSm, blk, 0, stream>>>(Cb, D, A, ND, ND, Cb, E, nullptr);

        build_skew<<<gSkew, blk, 0, stream>>>(u1, B);
        gemm_bt<EPI_NEG, false, false><<<gSm, blk, 0, stream>>>(B, B, Cb, ND, ND, nullptr, nullptr, nullptr);
        gemm_bt<EPI_ADD1, false, false><<<gSm, blk, 0, stream>>>(Cb, Cb, D, ND, ND, Cb, nullptr, nullptr);
        build_hoff<<<gElem, blk, 0, stream>>>(B, Cb, E, B);
        gemm_bt<EPI_P_ROT, false, false><<<gSm, blk, 0, stream>>>(E, D, Cb, ND, ND, D, E, th);

        gemm_bt<EPI_PLAIN, false, false><<<gSm, blk, 0, stream>>>(A, Cb, D, ND, ND, nullptr, nullptr, nullptr);
        gemm_bt<EPI_PLAIN, true, true><<<gBig, blk, 0, stream>>>(x, D, out, ND, ND, nullptr, nullptr, nullptr);
    }
}